// Round 1
// baseline (10324.799 us; speedup 1.0000x reference)
//
#include <hip/hip_runtime.h>
#include <hip/hip_bf16.h>

#define NB     64
#define LSEQ   1024
#define DIM    256
#define HDIM   256
#define KDIM   512
#define NGROUP 4
#define GROWS  16
#define NSLICE 16

typedef __attribute__((ext_vector_type(8))) short short8;
typedef __attribute__((ext_vector_type(4))) float f32x4;

__device__ __forceinline__ short f2bf(float f) {
    unsigned u = __builtin_bit_cast(unsigned, f);
    u += 0x7fffu + ((u >> 16) & 1u);
    return (short)(u >> 16);
}
__device__ __forceinline__ float bf2f(unsigned short s) {
    unsigned u = ((unsigned)s) << 16;
    return __builtin_bit_cast(float, u);
}
__device__ __forceinline__ float sigm(float x) {
    return __fdividef(1.f, 1.f + __expf(-x));
}

extern "C" __global__ void __launch_bounds__(448)
ctlstm_kernel(const float* __restrict__ x, const float* __restrict__ td,
              const float* __restrict__ Wi, const float* __restrict__ bi,
              const float* __restrict__ Wf, const float* __restrict__ bf,
              const float* __restrict__ Wie, const float* __restrict__ bie,
              const float* __restrict__ Wfe, const float* __restrict__ bfe,
              const float* __restrict__ Wz, const float* __restrict__ bz,
              const float* __restrict__ Wo, const float* __restrict__ bo,
              const float* __restrict__ Wd, const float* __restrict__ bdp,
              const float* __restrict__ betap,
              float* __restrict__ out,
              int* __restrict__ flags, unsigned short* __restrict__ hbuf)
{
    const int blk = blockIdx.x;
    const int g   = blk >> 4;          // row group 0..3
    const int s   = blk & 15;          // hidden slice 0..15
    const int brow0 = g * GROWS;
    const int j0    = s * 16;
    const int tid  = threadIdx.x;
    const int wave = tid >> 6;         // 0..6
    const int lane = tid & 63;
    const int l16  = lane & 15;
    const int lhi  = lane >> 4;

    __shared__ float tiles[6][16][17];   // [gate][batch_row][j] padded
    __shared__ float wd_lds[KDIM];

    for (int i = tid; i < KDIM; i += 448) wd_lds[i] = Wd[i];

    // ---- W fragments resident in VGPRs (waves 0-5) ----
    short8 wfrag[16];
    float bias = 0.f;
    if (wave < 6) {
        const float* Wg; const float* bg;
        switch (wave) {
            case 0: Wg = Wi;  bg = bi;  break;
            case 1: Wg = Wf;  bg = bf;  break;
            case 2: Wg = Wie; bg = bie; break;
            case 3: Wg = Wfe; bg = bfe; break;
            case 4: Wg = Wz;  bg = bz;  break;
            default: Wg = Wo; bg = bo;  break;
        }
        const int col = j0 + l16;
        bias = bg[col];
        #pragma unroll
        for (int kk = 0; kk < 16; ++kk) {
            short8 f;
            #pragma unroll
            for (int i = 0; i < 8; ++i) {
                const int k = kk * 32 + lhi * 8 + i;
                f[i] = f2bf(Wg[k * HDIM + col]);
            }
            wfrag[kk] = f;
        }
    }
    const float bd   = bdp[0];
    const float beta = betap[0];

    __syncthreads();

    // wave-6 carried state (per lane: batch row = l16, hidden j = j0 + lhi*4 + q)
    float cC[4]   = {0.f, 0.f, 0.f, 0.f};
    float ceS[4]  = {0.f, 0.f, 0.f, 0.f};
    float hreg[4] = {0.f, 0.f, 0.f, 0.f};
    float dnew    = 0.f;

    const float* xrow = x + (size_t)(brow0 + l16) * LSEQ * DIM;

    // prefetch x frags for t=0
    f32x4 xlo[8], xhi[8];
    if (wave < 6) {
        #pragma unroll
        for (int kk = 0; kk < 8; ++kk) {
            const float* p = xrow + kk * 32 + lhi * 8;
            xlo[kk] = *(const f32x4*)p;
            xhi[kk] = *(const f32x4*)(p + 4);
        }
    }

    for (int t = 0; t < LSEQ; ++t) {
        f32x4 acc = {bias, bias, bias, bias};
        float dpart = 0.f;

        if (wave < 6) {
            // convert prefetched x, prefetch next, run x-part MFMAs (k 0..255)
            short8 afr[8];
            #pragma unroll
            for (int kk = 0; kk < 8; ++kk) {
                short8 a;
                #pragma unroll
                for (int i = 0; i < 4; ++i) a[i] = f2bf(xlo[kk][i]);
                #pragma unroll
                for (int i = 0; i < 4; ++i) a[4 + i] = f2bf(xhi[kk][i]);
                afr[kk] = a;
            }
            if (t + 1 < LSEQ) {
                const float* p2 = xrow + (size_t)(t + 1) * DIM;
                #pragma unroll
                for (int kk = 0; kk < 8; ++kk) {
                    xlo[kk] = *(const f32x4*)(p2 + kk * 32 + lhi * 8);
                    xhi[kk] = *(const f32x4*)(p2 + kk * 32 + lhi * 8 + 4);
                }
            }
            #pragma unroll
            for (int kk = 0; kk < 8; ++kk)
                acc = __builtin_amdgcn_mfma_f32_16x16x32_bf16(afr[kk], wfrag[kk], acc, 0, 0, 0);
        } else {
            // wave 6: x-part of delta-head dot, then poll for h_t
            const float* p = xrow + (size_t)t * DIM;
            float dp = 0.f;
            #pragma unroll
            for (int kk = 0; kk < 8; ++kk) {
                f32x4 a = *(const f32x4*)(p + kk * 32 + lhi * 8);
                f32x4 b = *(const f32x4*)(p + kk * 32 + lhi * 8 + 4);
                const float* wdp = &wd_lds[kk * 32 + lhi * 8];
                dp += a[0]*wdp[0] + a[1]*wdp[1] + a[2]*wdp[2] + a[3]*wdp[3]
                    + b[0]*wdp[4] + b[1]*wdp[5] + b[2]*wdp[6] + b[3]*wdp[7];
            }
            dpart = dp;
            if (t >= 1) {
                const int fidx = (g * 16 + l16) * 32;
                int v;
                do {
                    v = __hip_atomic_load(&flags[fidx], __ATOMIC_RELAXED, __HIP_MEMORY_SCOPE_AGENT);
                } while (__any(v < t));
            }
        }

        __syncthreads();   // sync1: h_t ready; tiles(t-1) consumed

        if (wave < 6) {
            if (t >= 1) {
                const unsigned short* hrow =
                    hbuf + (size_t)(((t & 1) * NGROUP + g) * GROWS + l16) * HDIM;
                unsigned long long hq[8][2];
                #pragma unroll
                for (int kk = 0; kk < 8; ++kk) {
                    const unsigned long long* hp =
                        (const unsigned long long*)(hrow + kk * 32 + lhi * 8);
                    hq[kk][0] = __hip_atomic_load(hp,     __ATOMIC_RELAXED, __HIP_MEMORY_SCOPE_AGENT);
                    hq[kk][1] = __hip_atomic_load(hp + 1, __ATOMIC_RELAXED, __HIP_MEMORY_SCOPE_AGENT);
                }
                #pragma unroll
                for (int kk = 0; kk < 8; ++kk) {
                    union { unsigned long long q[2]; short8 v; } u;
                    u.q[0] = hq[kk][0]; u.q[1] = hq[kk][1];
                    acc = __builtin_amdgcn_mfma_f32_16x16x32_bf16(u.v, wfrag[8 + kk], acc, 0, 0, 0);
                }
            }
            float gv[4];
            #pragma unroll
            for (int q = 0; q < 4; ++q) gv[q] = acc[q];
            if (wave == 4) {   // z = 2*sigmoid(g) - 1
                #pragma unroll
                for (int q = 0; q < 4; ++q)
                    gv[q] = 1.f - 2.f * __fdividef(1.f, 1.f + __expf(gv[q]));
            } else {
                #pragma unroll
                for (int q = 0; q < 4; ++q) gv[q] = sigm(gv[q]);
            }
            #pragma unroll
            for (int q = 0; q < 4; ++q) tiles[wave][lhi * 4 + q][l16] = gv[q];
        } else {
            if (t >= 1) {   // h-part of delta-head dot
                const unsigned short* hrow =
                    hbuf + (size_t)(((t & 1) * NGROUP + g) * GROWS + l16) * HDIM;
                float dp = 0.f;
                #pragma unroll
                for (int kk = 0; kk < 8; ++kk) {
                    const unsigned long long* hp =
                        (const unsigned long long*)(hrow + kk * 32 + lhi * 8);
                    unsigned long long q0 = __hip_atomic_load(hp,     __ATOMIC_RELAXED, __HIP_MEMORY_SCOPE_AGENT);
                    unsigned long long q1 = __hip_atomic_load(hp + 1, __ATOMIC_RELAXED, __HIP_MEMORY_SCOPE_AGENT);
                    const float* wdp = &wd_lds[DIM + kk * 32 + lhi * 8];
                    #pragma unroll
                    for (int i = 0; i < 4; ++i) dp += bf2f((unsigned short)(q0 >> (16 * i))) * wdp[i];
                    #pragma unroll
                    for (int i = 0; i < 4; ++i) dp += bf2f((unsigned short)(q1 >> (16 * i))) * wdp[4 + i];
                }
                dpart += dp;
            }
            dpart += __shfl_xor(dpart, 16);
            dpart += __shfl_xor(dpart, 32);
            const float gd  = dpart + bd;
            const float bg_ = beta * gd;
            const float sp  = fmaxf(bg_, 0.f) + __logf(1.f + __expf(-fabsf(bg_)));
            dnew = sp / beta;
        }

        __syncthreads();   // sync2: gate tiles ready

        if (wave == 6) {
            float ig[4], fg[4], ieg[4], feg[4], zg[4], og[4];
            #pragma unroll
            for (int q = 0; q < 4; ++q) {
                const int jj = lhi * 4 + q;
                ig[q]  = tiles[0][l16][jj];
                fg[q]  = tiles[1][l16][jj];
                ieg[q] = tiles[2][l16][jj];
                feg[q] = tiles[3][l16][jj];
                zg[q]  = tiles[4][l16][jj];
                og[q]  = tiles[5][l16][jj];
            }
            float cs[4];
            #pragma unroll
            for (int q = 0; q < 4; ++q) {
                cs[q]  = fg[q] * cC[q] + ig[q] * zg[q];
                ceS[q] = feg[q] * ceS[q] + ieg[q] * zg[q];
            }
            // outputs[:, t, slice] = H[t]
            {
                f32x4 hv = {hreg[0], hreg[1], hreg[2], hreg[3]};
                *(f32x4*)(out + ((size_t)(brow0 + l16) * LSEQ + t) * HDIM + j0 + lhi * 4) = hv;
            }
            if (t + 1 < LSEQ) {
                const float dtv = td[(size_t)(brow0 + l16) * LSEQ + (t + 1)];
                const float e   = __expf(-dnew * dtv);
                unsigned long long pk = 0;
                #pragma unroll
                for (int q = 0; q < 4; ++q) {
                    const float cn = cs[q] + (ceS[q] - cs[q]) * e;
                    cC[q] = cn;
                    const float hv = og[q] * (1.f - 2.f * __fdividef(1.f, 1.f + __expf(2.f * cn)));
                    hreg[q] = hv;
                    pk |= ((unsigned long long)(unsigned short)f2bf(hv)) << (16 * q);
                }
                unsigned long long* hp = (unsigned long long*)
                    (hbuf + (size_t)((((t + 1) & 1) * NGROUP + g) * GROWS + l16) * HDIM + j0 + lhi * 4);
                __hip_atomic_store(hp, pk, __ATOMIC_RELAXED, __HIP_MEMORY_SCOPE_AGENT);
                asm volatile("s_waitcnt vmcnt(0)" ::: "memory");
                if (lane == 0)
                    __hip_atomic_store(&flags[(g * 16 + s) * 32], t + 1,
                                       __ATOMIC_RELAXED, __HIP_MEMORY_SCOPE_AGENT);
            } else {
                float* so = out + (size_t)NB * LSEQ * HDIM + (size_t)(brow0 + l16) * 769;
                #pragma unroll
                for (int q = 0; q < 4; ++q) {
                    const int jj = j0 + lhi * 4 + q;
                    so[jj]       = og[q];
                    so[256 + jj] = cs[q];
                    so[512 + jj] = ceS[q];
                }
                if (s == 0 && lane < 16) so[768] = dnew;
            }
        }
    }
}

extern "C" void kernel_launch(void* const* d_in, const int* in_sizes, int n_in,
                              void* d_out, int out_size, void* d_ws, size_t ws_size,
                              hipStream_t stream) {
    const float* x   = (const float*)d_in[0];
    const float* td  = (const float*)d_in[1];
    const float* Wi  = (const float*)d_in[2];
    const float* bi  = (const float*)d_in[3];
    const float* Wf  = (const float*)d_in[4];
    const float* bf  = (const float*)d_in[5];
    const float* Wie = (const float*)d_in[6];
    const float* bie = (const float*)d_in[7];
    const float* Wfe = (const float*)d_in[8];
    const float* bfe = (const float*)d_in[9];
    const float* Wz  = (const float*)d_in[10];
    const float* bz  = (const float*)d_in[11];
    const float* Wo  = (const float*)d_in[12];
    const float* bo  = (const float*)d_in[13];
    const float* Wd  = (const float*)d_in[14];
    const float* bd  = (const float*)d_in[15];
    const float* be  = (const float*)d_in[16];

    int* flags = (int*)d_ws;                                   // 64 flags * 128B
    unsigned short* hbuf = (unsigned short*)((char*)d_ws + 8192); // 2*4*16*256 bf16

    hipMemsetAsync(d_ws, 0, 8192, stream);
    hipLaunchKernelGGL(ctlstm_kernel, dim3(64), dim3(448), 0, stream,
                       x, td, Wi, bi, Wf, bf, Wie, bie, Wfe, bfe, Wz, bz, Wo, bo,
                       Wd, bd, be, (float*)d_out, flags, hbuf);
}